// Round 4
// baseline (90.694 us; speedup 1.0000x reference)
//
#include <hip/hip_runtime.h>
#include <hip/hip_bf16.h>
#include <stdint.h>

// CrossAttentionHead: B=8,S=2048,D=1024,HS=64, fp32 in/out, bf16 MFMA internally.
// k0: W -> bf16 fragment-swizzled (scale folded into Wq)
// k1: projections, 4-way K-split per 16-row tile. R3: FULL register preload
//     (xa[16] X-slice + wr[32] W-fragments) fenced by sched_barrier(0) so the
//     compiler cannot sink the loads (R2 showed VGPR=32 -> loads serialized).
// k2: flash attention, causal, 4-way k-split per q-tile (flash-decoding merge)

#define NB  8
#define SEQ 2048
#define DIM 1024
#define HSZ 64

typedef short bf16x8 __attribute__((ext_vector_type(8)));
typedef short s16x4  __attribute__((ext_vector_type(4)));
typedef float f32x4  __attribute__((ext_vector_type(4)));

__device__ __forceinline__ short f2bf(float f) {
  uint32_t u = __builtin_bit_cast(uint32_t, f);
  u = (u + 0x7fffu + ((u >> 16) & 1u)) >> 16;   // RNE
  return (short)u;
}

// ---------------- Kernel 0: W -> bf16 B-fragment layout -------------------
// idx = (((w*32 + s)*4 + t)*64 + lane)*8 + i
// val = W[k][n]*scale, k = s*32 + (lane>>4)*8 + i, n = t*16 + (lane&15)
__global__ void w_prep(const float* __restrict__ Wq, const float* __restrict__ Wk,
                       const float* __restrict__ Wv, short* __restrict__ wfrag) {
  const int total = 3 << 16;
  for (int e = blockIdx.x * blockDim.x + threadIdx.x; e < total;
       e += gridDim.x * blockDim.x) {
    int i = e & 7, l = (e >> 3) & 63, t = (e >> 9) & 3, s = (e >> 11) & 31, w = e >> 16;
    const float* W = (w == 0) ? Wq : (w == 1) ? Wk : Wv;
    float scale = (w == 0) ? 0.125f : 1.0f;   // fold HS^-0.5 into Wq
    int k = s * 32 + (l >> 4) * 8 + i;
    int n = t * 16 + (l & 15);
    wfrag[e] = f2bf(W[k * HSZ + n] * scale);
  }
}

// ---------------- Kernel 1: projections -----------------------------------
// grid (1024, 3), block 256 (4 waves). Block owns a 16-row x 64-col tile;
// wave w accumulates K in [w*256, w*256+256), then LDS cross-wave reduce.
// Entire per-wave input (16 X dwordx4 + 32 W dwordx4) is preloaded into
// registers behind a sched_barrier(0): ~48 loads in flight per wave.
__global__ __launch_bounds__(256, 2) void proj(const float* __restrict__ Xq,
                                               const float* __restrict__ Xk,
                                               const float* __restrict__ Xv,
                                               const short* __restrict__ wfrag,
                                               short* __restrict__ qb,
                                               short* __restrict__ kbuf,
                                               short* __restrict__ vT) {
  __shared__ f32x4 red[4][16 * 17];   // [wave][row*17 + colgroup], f32 stride 68
  const int tid = threadIdx.x;
  const int wave = tid >> 6, lane = tid & 63;
  const int hi = lane >> 4, lo = lane & 15;
  const int which = blockIdx.y;
  const float* X = (which == 0) ? Xq : (which == 1) ? Xk : Xv;
  const short* wf = wfrag + (which << 16);
  const int row0 = blockIdx.x * 16;
  const float* xp = X + (size_t)(row0 + lo) * DIM + wave * 256 + hi * 8;
  const short* wb0 = wf + (size_t)wave * 32 * 512 + lane * 8;

  // ---- preload whole per-wave working set: 48 loads in flight ----
  f32x4 xa[16];
#pragma unroll
  for (int s8 = 0; s8 < 8; ++s8) {
    xa[2 * s8]     = *(const f32x4*)(xp + s8 * 32);
    xa[2 * s8 + 1] = *(const f32x4*)(xp + s8 * 32 + 4);
  }
  bf16x8 wr[32];
#pragma unroll
  for (int j = 0; j < 32; ++j)
    wr[j] = *(const bf16x8*)(wb0 + (size_t)j * 512);
  __builtin_amdgcn_sched_barrier(0);   // nothing moves across: loads stay hoisted

  f32x4 acc0 = {0.f, 0.f, 0.f, 0.f}, acc1 = acc0, acc2 = acc0, acc3 = acc0;
#pragma unroll
  for (int s8 = 0; s8 < 8; ++s8) {
    const f32x4 a0 = xa[2 * s8];
    const f32x4 a1 = xa[2 * s8 + 1];
    bf16x8 af;
    af[0] = f2bf(a0[0]); af[1] = f2bf(a0[1]); af[2] = f2bf(a0[2]); af[3] = f2bf(a0[3]);
    af[4] = f2bf(a1[0]); af[5] = f2bf(a1[1]); af[6] = f2bf(a1[2]); af[7] = f2bf(a1[3]);
    acc0 = __builtin_amdgcn_mfma_f32_16x16x32_bf16(af, wr[s8 * 4 + 0], acc0, 0, 0, 0);
    acc1 = __builtin_amdgcn_mfma_f32_16x16x32_bf16(af, wr[s8 * 4 + 1], acc1, 0, 0, 0);
    acc2 = __builtin_amdgcn_mfma_f32_16x16x32_bf16(af, wr[s8 * 4 + 2], acc2, 0, 0, 0);
    acc3 = __builtin_amdgcn_mfma_f32_16x16x32_bf16(af, wr[s8 * 4 + 3], acc3, 0, 0, 0);
  }

  // partials -> LDS
  float* redf = (float*)&red[wave][0];
#pragma unroll
  for (int r = 0; r < 4; ++r) {
    const int row = hi * 4 + r;
    redf[row * 68 + lo]      = acc0[r];
    redf[row * 68 + 16 + lo] = acc1[r];
    redf[row * 68 + 32 + lo] = acc2[r];
    redf[row * 68 + 48 + lo] = acc3[r];
  }
  __syncthreads();

  if (which < 2) {
    short* ob = (which == 0) ? qb : kbuf;
    const int row = tid >> 4, cg = tid & 15;
    const f32x4 s = red[0][row * 17 + cg] + red[1][row * 17 + cg] +
                    red[2][row * 17 + cg] + red[3][row * 17 + cg];
    s16x4 p;
    p[0] = f2bf(s[0]); p[1] = f2bf(s[1]); p[2] = f2bf(s[2]); p[3] = f2bf(s[3]);
    *(s16x4*)(ob + (size_t)(row0 + row) * HSZ + cg * 4) = p;
  } else {
    const int col = tid & 63, g = tid >> 6;
    s16x4 p;
#pragma unroll
    for (int j = 0; j < 4; ++j) {
      const int row = g * 4 + j;
      float v = ((float*)&red[0][0])[row * 68 + col] +
                ((float*)&red[1][0])[row * 68 + col] +
                ((float*)&red[2][0])[row * 68 + col] +
                ((float*)&red[3][0])[row * 68 + col];
      p[j] = f2bf(v);
    }
    *(s16x4*)(vT + (size_t)(row0 >> 11) * (HSZ * SEQ) + (size_t)col * SEQ +
              (row0 & (SEQ - 1)) + g * 4) = p;
  }
}

// ---------------- Kernel 2: causal flash attention -------------------------
// grid 1024 (one block per 16-row q-tile, heavy tiles first), block 256.
// 4 waves split the causal k-block range; flash-decoding merge in LDS.
__global__ __launch_bounds__(256) void attn(const short* __restrict__ qb,
                                            const short* __restrict__ kbuf,
                                            const short* __restrict__ vT,
                                            float* __restrict__ out) {
  __shared__ short plds[4][16 * 32];   // wave-private P staging (bf16)
  __shared__ f32x4 ored[4][16 * 17];   // o partials, f32 stride 68
  __shared__ float mred[4][16];
  __shared__ float lred[4][16];
  const int tid = threadIdx.x;
  const int wave = tid >> 6, lane = tid & 63;
  const int hi = lane >> 4, lo = lane & 15;
  const int bid = blockIdx.x;
  const int tq = 127 - (bid >> 3);    // heavy q-tiles dispatched first
  const int b  = bid & 7;
  const int q0 = tq * 16;

  const short* qp = qb + (size_t)(b * SEQ + q0 + lo) * HSZ + hi * 8;
  const bf16x8 qf0 = *(const bf16x8*)qp;
  const bf16x8 qf1 = *(const bf16x8*)(qp + 32);

  f32x4 o0 = {0.f, 0.f, 0.f, 0.f}, o1 = o0, o2 = o0, o3 = o0;
  f32x4 mrow = {-1e30f, -1e30f, -1e30f, -1e30f};
  f32x4 lrow = {0.f, 0.f, 0.f, 0.f};

  const short* kb_ = kbuf + (size_t)b * SEQ * HSZ;
  const short* vb_ = vT + (size_t)b * HSZ * SEQ;
  short* pl = plds[wave];
  const int nkb = (q0 + 47) >> 5;
  const int chunk = (nkb + 3) >> 2;
  const int kks = wave * chunk;
  const int kke = min(kks + chunk, nkb);

  for (int kk = kks; kk < kke; ++kk) {
    const int kc0 = kk * 32;
    const short* kr0 = kb_ + (size_t)(kc0 + lo) * HSZ + hi * 8;
    const short* kr1 = kr0 + 16 * HSZ;
    f32x4 s0v = {0.f, 0.f, 0.f, 0.f}, s1v = s0v;
    s0v = __builtin_amdgcn_mfma_f32_16x16x32_bf16(qf0, *(const bf16x8*)kr0, s0v, 0, 0, 0);
    s0v = __builtin_amdgcn_mfma_f32_16x16x32_bf16(qf1, *(const bf16x8*)(kr0 + 32), s0v, 0, 0, 0);
    s1v = __builtin_amdgcn_mfma_f32_16x16x32_bf16(qf0, *(const bf16x8*)kr1, s1v, 0, 0, 0);
    s1v = __builtin_amdgcn_mfma_f32_16x16x32_bf16(qf1, *(const bf16x8*)(kr1 + 32), s1v, 0, 0, 0);

    const bool edge = (kc0 + 31 > q0);
#pragma unroll
    for (int r = 0; r < 4; ++r) {
      const int row = q0 + hi * 4 + r;
      float s0 = s0v[r], s1 = s1v[r];
      if (edge) {
        if (kc0 + lo > row)      s0 = -1e30f;
        if (kc0 + 16 + lo > row) s1 = -1e30f;
      }
      float pm = fmaxf(s0, s1);
      pm = fmaxf(pm, __shfl_xor(pm, 1, 16));
      pm = fmaxf(pm, __shfl_xor(pm, 2, 16));
      pm = fmaxf(pm, __shfl_xor(pm, 4, 16));
      pm = fmaxf(pm, __shfl_xor(pm, 8, 16));
      const float mn  = fmaxf(mrow[r], pm);
      const float fac = __expf(mrow[r] - mn);
      mrow[r] = mn;
      const float p0 = __expf(s0 - mn), p1 = __expf(s1 - mn);
      float ps = p0 + p1;
      ps += __shfl_xor(ps, 1, 16);
      ps += __shfl_xor(ps, 2, 16);
      ps += __shfl_xor(ps, 4, 16);
      ps += __shfl_xor(ps, 8, 16);
      lrow[r] = lrow[r] * fac + ps;
      o0[r] *= fac; o1[r] *= fac; o2[r] *= fac; o3[r] *= fac;
      pl[(hi * 4 + r) * 32 + lo]      = f2bf(p0);
      pl[(hi * 4 + r) * 32 + 16 + lo] = f2bf(p1);
    }
    const bf16x8 pa = *(const bf16x8*)(pl + lo * 32 + hi * 8);
    const short* vr = vb_ + (size_t)lo * SEQ + kc0 + hi * 8;
    o0 = __builtin_amdgcn_mfma_f32_16x16x32_bf16(pa, *(const bf16x8*)(vr), o0, 0, 0, 0);
    o1 = __builtin_amdgcn_mfma_f32_16x16x32_bf16(pa, *(const bf16x8*)(vr + 16 * SEQ), o1, 0, 0, 0);
    o2 = __builtin_amdgcn_mfma_f32_16x16x32_bf16(pa, *(const bf16x8*)(vr + 32 * SEQ), o2, 0, 0, 0);
    o3 = __builtin_amdgcn_mfma_f32_16x16x32_bf16(pa, *(const bf16x8*)(vr + 48 * SEQ), o3, 0, 0, 0);
  }

  // partials -> LDS
  float* redf = (float*)&ored[wave][0];
#pragma unroll
  for (int r = 0; r < 4; ++r) {
    const int row = hi * 4 + r;
    redf[row * 68 + lo]      = o0[r];
    redf[row * 68 + 16 + lo] = o1[r];
    redf[row * 68 + 32 + lo] = o2[r];
    redf[row * 68 + 48 + lo] = o3[r];
  }
  if (lo == 0) {
#pragma unroll
    for (int r = 0; r < 4; ++r) {
      mred[wave][hi * 4 + r] = mrow[r];
      lred[wave][hi * 4 + r] = lrow[r];
    }
  }
  __syncthreads();

  // flash-decoding merge across the 4 k-splits
  const int row = tid >> 4, cg = tid & 15;
  float mv0 = mred[0][row], mv1 = mred[1][row], mv2 = mred[2][row], mv3 = mred[3][row];
  float M = fmaxf(fmaxf(mv0, mv1), fmaxf(mv2, mv3));
  const float w0 = __expf(mv0 - M), w1 = __expf(mv1 - M);
  const float w2 = __expf(mv2 - M), w3 = __expf(mv3 - M);
  const float L = lred[0][row] * w0 + lred[1][row] * w1 +
                  lred[2][row] * w2 + lred[3][row] * w3;
  f32x4 acc = ored[0][row * 17 + cg] * w0 + ored[1][row * 17 + cg] * w1 +
              ored[2][row * 17 + cg] * w2 + ored[3][row * 17 + cg] * w3;
  acc *= (1.0f / L);
  *(f32x4*)(out + ((size_t)(b * SEQ + q0 + row)) * HSZ + cg * 4) = acc;
}

extern "C" void kernel_launch(void* const* d_in, const int* in_sizes, int n_in,
                              void* d_out, int out_size, void* d_ws, size_t ws_size,
                              hipStream_t stream) {
  const float* query = (const float*)d_in[0];
  const float* key   = (const float*)d_in[1];
  const float* value = (const float*)d_in[2];
  const float* Wq    = (const float*)d_in[3];
  const float* Wk    = (const float*)d_in[4];
  const float* Wv    = (const float*)d_in[5];

  char* ws = (char*)d_ws;
  short* wfrag = (short*)ws;                                  // 384 KiB
  short* qb    = (short*)(ws + (3 << 17));                    // 2 MiB
  short* kb    = (short*)(ws + (3 << 17) + (1 << 21));        // 2 MiB
  short* vT    = (short*)(ws + (3 << 17) + (2 << 21));        // 2 MiB
  float* outp  = (float*)d_out;

  hipLaunchKernelGGL(w_prep, dim3(64), dim3(256), 0, stream, Wq, Wk, Wv, wfrag);
  hipLaunchKernelGGL(proj, dim3(1024, 3), dim3(256), 0, stream,
                     query, key, value, wfrag, qb, kb, vT);
  hipLaunchKernelGGL(attn, dim3(1024), dim3(256), 0, stream, qb, kb, vT, outp);
}

// Round 5
// 83.345 us; speedup vs baseline: 1.0882x; 1.0882x over previous
//
#include <hip/hip_runtime.h>
#include <hip/hip_bf16.h>
#include <stdint.h>

// CrossAttentionHead: B=8,S=2048,D=1024,HS=64, fp32 in/out, bf16 MFMA internally.
// k0: W -> bf16 fragment-swizzled (scale folded into Wq)
// k1: projections — m97-style global_load_lds double-buffered GEMM.
//     64x64 tile/block, BK=64, X tile XOR-swizzled (16B granules, pre-swizzled
//     global source), W frag tile staged linearly. R1-R3 showed VGPR-staged
//     loads get serialized by the compiler (latency-bound at 1.5 TB/s even
//     L3-resident); direct-to-LDS loads are fire-and-forget -> deep MLP.
// k2: flash attention, causal, 4-way k-split per q-tile (flash-decoding merge)

#define NB  8
#define SEQ 2048
#define DIM 1024
#define HSZ 64

typedef short bf16x8 __attribute__((ext_vector_type(8)));
typedef short s16x4  __attribute__((ext_vector_type(4)));
typedef float f32x4  __attribute__((ext_vector_type(4)));

__device__ __forceinline__ short f2bf(float f) {
  uint32_t u = __builtin_bit_cast(uint32_t, f);
  u = (u + 0x7fffu + ((u >> 16) & 1u)) >> 16;   // RNE
  return (short)u;
}

__device__ __forceinline__ void gload_lds16(const void* g, void* l) {
  __builtin_amdgcn_global_load_lds(
      (const __attribute__((address_space(1))) void*)g,
      (__attribute__((address_space(3))) void*)l, 16, 0, 0);
}

// ---------------- Kernel 0: W -> bf16 B-fragment layout -------------------
// idx = (((w*32 + s)*4 + t)*64 + lane)*8 + i
// val = W[k][n]*scale, k = s*32 + (lane>>4)*8 + i, n = t*16 + (lane&15)
__global__ void w_prep(const float* __restrict__ Wq, const float* __restrict__ Wk,
                       const float* __restrict__ Wv, short* __restrict__ wfrag) {
  const int total = 3 << 16;
  for (int e = blockIdx.x * blockDim.x + threadIdx.x; e < total;
       e += gridDim.x * blockDim.x) {
    int i = e & 7, l = (e >> 3) & 63, t = (e >> 9) & 3, s = (e >> 11) & 31, w = e >> 16;
    const float* W = (w == 0) ? Wq : (w == 1) ? Wk : Wv;
    float scale = (w == 0) ? 0.125f : 1.0f;   // fold HS^-0.5 into Wq
    int k = s * 32 + (l >> 4) * 8 + i;
    int n = t * 16 + (l & 15);
    wfrag[e] = f2bf(W[k * HSZ + n] * scale);
  }
}

// ---------------- Kernel 1: projections -----------------------------------
// grid (256, 3), block 256 (4 waves). Block tile: 64 rows x 64 cols, K=1024
// in 16 steps of 64. X tile 16KB + W tile 8KB, double-buffered (48KB LDS,
// 3 blocks/CU). Staging via global_load_lds width=16. Wave w owns rows
// w*16..w*16+15 for the FULL K (no cross-wave reduce).
__global__ __launch_bounds__(256, 3) void proj(const float* __restrict__ Xq,
                                               const float* __restrict__ Xk,
                                               const float* __restrict__ Xv,
                                               const short* __restrict__ wfrag,
                                               short* __restrict__ qb,
                                               short* __restrict__ kbuf,
                                               short* __restrict__ vT) {
  __shared__ char xbuf[2][16384];   // [row 0..63][64 f32], 16B-granule XOR swizzle
  __shared__ char wbuf[2][8192];    // 8 B-frags (2 ksub x 4 ncol), lane-linear
  const int tid = threadIdx.x;
  const int wave = tid >> 6, lane = tid & 63;
  const int hi = lane >> 4, lo = lane & 15;
  const int which = blockIdx.y;
  const float* X = (which == 0) ? Xq : (which == 1) ? Xk : Xv;
  const char* wf = (const char*)(wfrag + (which << 16));
  const int row0 = blockIdx.x * 64;

  // --- staging: LDS dest linear (HW: wave-uniform base + lane*16);
  //     X global source pre-swizzled so reads can XOR-deswizzle (rule #21).
  const int srow = tid >> 4;            // 0..15, + i*16
  const int sg   = tid & 15;            // 16B slot within row
#define STAGE(kt, pb)                                                          \
  {                                                                            \
    _Pragma("unroll")                                                          \
    for (int i = 0; i < 4; ++i) {                                              \
      const int rw = i * 16 + srow;                                            \
      const int g  = sg ^ (rw & 7);                                            \
      gload_lds16(X + (size_t)(row0 + rw) * DIM + (kt) * 64 + g * 4,           \
                  &xbuf[pb][i * 4096 + tid * 16]);                             \
    }                                                                          \
    _Pragma("unroll")                                                          \
    for (int j = 0; j < 2; ++j)                                                \
      gload_lds16(wf + (kt) * 8192 + j * 4096 + tid * 16,                      \
                  &wbuf[pb][j * 4096 + tid * 16]);                             \
  }

  f32x4 acc0 = {0.f, 0.f, 0.f, 0.f}, acc1 = acc0, acc2 = acc0, acc3 = acc0;

  STAGE(0, 0);
  asm volatile("s_waitcnt vmcnt(0)" ::: "memory");
  __syncthreads();

  for (int kt = 0; kt < 16; ++kt) {
    const int cur = kt & 1;
    if (kt < 15) STAGE(kt + 1, cur ^ 1);
    const char* xb = xbuf[cur] + wave * 4096 + lo * 256;  // this lane's row
    const char* wb = wbuf[cur] + lane * 16;
#pragma unroll
    for (int s = 0; s < 2; ++s) {
      const int gb = s * 8 + hi * 2;
      const f32x4 a0 = *(const f32x4*)(xb + ((gb)     ^ (lo & 7)) * 16);
      const f32x4 a1 = *(const f32x4*)(xb + ((gb + 1) ^ (lo & 7)) * 16);
      bf16x8 af;
      af[0] = f2bf(a0[0]); af[1] = f2bf(a0[1]); af[2] = f2bf(a0[2]); af[3] = f2bf(a0[3]);
      af[4] = f2bf(a1[0]); af[5] = f2bf(a1[1]); af[6] = f2bf(a1[2]); af[7] = f2bf(a1[3]);
      acc0 = __builtin_amdgcn_mfma_f32_16x16x32_bf16(af, *(const bf16x8*)(wb + (s*4+0)*1024), acc0, 0, 0, 0);
      acc1 = __builtin_amdgcn_mfma_f32_16x16x32_bf16(af, *(const bf16x8*)(wb + (s*4+1)*1024), acc1, 0, 0, 0);
      acc2 = __builtin_amdgcn_mfma_f32_16x16x32_bf16(af, *(const bf16x8*)(wb + (s*4+2)*1024), acc2, 0, 0, 0);
      acc3 = __builtin_amdgcn_mfma_f32_16x16x32_bf16(af, *(const bf16x8*)(wb + (s*4+3)*1024), acc3, 0, 0, 0);
    }
    asm volatile("s_waitcnt vmcnt(0)" ::: "memory");
    __syncthreads();
  }
#undef STAGE

  // --- epilogue: C-layout col = lane&15, row = (lane>>4)*4 + r ---
  if (which < 2) {
    short* ob = (which == 0) ? qb : kbuf;
#pragma unroll
    for (int r = 0; r < 4; ++r) {
      const size_t base = (size_t)(row0 + wave * 16 + hi * 4 + r) * HSZ + lo;
      ob[base +  0] = f2bf(acc0[r]);
      ob[base + 16] = f2bf(acc1[r]);
      ob[base + 32] = f2bf(acc2[r]);
      ob[base + 48] = f2bf(acc3[r]);
    }
  } else {
    // transpose 16x64 through retired xbuf[0], then 32B-contiguous vT stores
    short* lv = (short*)&xbuf[0][wave * 2048];   // [col 0..63][row 0..15]
#pragma unroll
    for (int r = 0; r < 4; ++r) {
      const int row = hi * 4 + r;
      lv[(lo)      * 16 + row] = f2bf(acc0[r]);
      lv[(16 + lo) * 16 + row] = f2bf(acc1[r]);
      lv[(32 + lo) * 16 + row] = f2bf(acc2[r]);
      lv[(48 + lo) * 16 + row] = f2bf(acc3[r]);
    }
    __syncthreads();
    const short* src = lv + lane * 16;           // col = lane, rows 0..15
    short* dst = vT + (size_t)(row0 >> 11) * (HSZ * SEQ) + (size_t)lane * SEQ +
                 ((row0 + wave * 16) & (SEQ - 1));
    *(bf16x8*)dst       = *(const bf16x8*)src;
    *(bf16x8*)(dst + 8) = *(const bf16x8*)(src + 8);
  }
}

// ---------------- Kernel 2: causal flash attention -------------------------
// grid 1024 (one block per 16-row q-tile, heavy tiles first), block 256.
// 4 waves split the causal k-block range; flash-decoding merge in LDS.
__global__ __launch_bounds__(256) void attn(const short* __restrict__ qb,
                                            const short* __restrict__ kbuf,
                                            const short* __restrict__ vT,
                                            float* __restrict__ out) {
  __shared__ short plds[4][16 * 32];   // wave-private P staging (bf16)
  __shared__ f32x4 ored[4][16 * 17];   // o partials, f32 stride 68
  __shared__ float mred[4][16];
  __shared__ float lred[4][16];
  const int tid = threadIdx.x;
  const int wave = tid >> 6, lane = tid & 63;
  const int hi = lane >> 4, lo = lane & 15;
  const int bid = blockIdx.x;
  const int tq = 127 - (bid >> 3);    // heavy q-tiles dispatched first
  const int b  = bid & 7;
  const int q0 = tq * 16;

  const short* qp = qb + (size_t)(b * SEQ + q0 + lo) * HSZ + hi * 8;
  const bf16x8 qf0 = *(const bf16x8*)qp;
  const bf16x8 qf1 = *(const bf16x8*)(qp + 32);

  f32x4 o0 = {0.f, 0.f, 0.f, 0.f}, o1 = o0, o2 = o0, o3 = o0;
  f32x4 mrow = {-1e30f, -1e30f, -1e30f, -1e30f};
  f32x4 lrow = {0.f, 0.f, 0.f, 0.f};

  const short* kb_ = kbuf + (size_t)b * SEQ * HSZ;
  const short* vb_ = vT + (size_t)b * HSZ * SEQ;
  short* pl = plds[wave];
  const int nkb = (q0 + 47) >> 5;
  const int chunk = (nkb + 3) >> 2;
  const int kks = wave * chunk;
  const int kke = min(kks + chunk, nkb);

  for (int kk = kks; kk < kke; ++kk) {
    const int kc0 = kk * 32;
    const short* kr0 = kb_ + (size_t)(kc0 + lo) * HSZ + hi * 8;
    const short* kr1 = kr0 + 16 * HSZ;
    f32x4 s0v = {0.f, 0.f, 0.f, 0.f}, s1v = s0v;
    s0v = __builtin_amdgcn_mfma_f32_16x16x32_bf16(qf0, *(const bf16x8*)kr0, s0v, 0, 0, 0);
    s0v = __builtin_amdgcn_mfma_f32_16x16x32_bf16(qf1, *(const bf16x8*)(kr0 + 32), s0v, 0, 0, 0);
    s1v = __builtin_amdgcn_mfma_f32_16x16x32_bf16(qf0, *(const bf16x8*)kr1, s1v, 0, 0, 0);
    s1v = __builtin_amdgcn_mfma_f32_16x16x32_bf16(qf1, *(const bf16x8*)(kr1 + 32), s1v, 0, 0, 0);

    const bool edge = (kc0 + 31 > q0);
#pragma unroll
    for (int r = 0; r < 4; ++r) {
      const int row = q0 + hi * 4 + r;
      float s0 = s0v[r], s1 = s1v[r];
      if (edge) {
        if (kc0 + lo > row)      s0 = -1e30f;
        if (kc0 + 16 + lo > row) s1 = -1e30f;
      }
      float pm = fmaxf(s0, s1);
      pm = fmaxf(pm, __shfl_xor(pm, 1, 16));
      pm = fmaxf(pm, __shfl_xor(pm, 2, 16));
      pm = fmaxf(pm, __shfl_xor(pm, 4, 16));
      pm = fmaxf(pm, __shfl_xor(pm, 8, 16));
      const float mn  = fmaxf(mrow[r], pm);
      const float fac = __expf(mrow[r] - mn);
      mrow[r] = mn;
      const float p0 = __expf(s0 - mn), p1 = __expf(s1 - mn);
      float ps = p0 + p1;
      ps += __shfl_xor(ps, 1, 16);
      ps += __shfl_xor(ps, 2, 16);
      ps += __shfl_xor(ps, 4, 16);
      ps += __shfl_xor(ps, 8, 16);
      lrow[r] = lrow[r] * fac + ps;
      o0[r] *= fac; o1[r] *= fac; o2[r] *= fac; o3[r] *= fac;
      pl[(hi * 4 + r) * 32 + lo]      = f2bf(p0);
      pl[(hi * 4 + r) * 32 + 16 + lo] = f2bf(p1);
    }
    const bf16x8 pa = *(const bf16x8*)(pl + lo * 32 + hi * 8);
    const short* vr = vb_ + (size_t)lo * SEQ + kc0 + hi * 8;
    o0 = __builtin_amdgcn_mfma_f32_16x16x32_bf16(pa, *(const bf16x8*)(vr), o0, 0, 0, 0);
    o1 = __builtin_amdgcn_mfma_f32_16x16x32_bf16(pa, *(const bf16x8*)(vr + 16 * SEQ), o1, 0, 0, 0);
    o2 = __builtin_amdgcn_mfma_f32_16x16x32_bf16(pa, *(const bf16x8*)(vr + 32 * SEQ), o2, 0, 0, 0);
    o3 = __builtin_amdgcn_mfma_f32_16x16x32_bf16(pa, *(const bf16x8*)(vr + 48 * SEQ), o3, 0, 0, 0);
  }

  // partials -> LDS
  float* redf = (float*)&ored[wave][0];
#pragma unroll
  for (int r = 0; r < 4; ++r) {
    const int row = hi * 4 + r;
    redf[row * 68 + lo]      = o0[r];
    redf[row * 68 + 16 + lo] = o1[r];
    redf[row * 68 + 32 + lo] = o2[r];
    redf[row * 68 + 48 + lo] = o3[r];
  }
  if (lo == 0) {
#pragma unroll
    for (int r = 0; r < 4; ++r) {
      mred[wave][hi * 4 + r] = mrow[r];
      lred[wave][hi * 4 + r] = lrow[r];
    }
  }
  __syncthreads();

  // flash-decoding merge across the 4 k-splits
  const int row = tid >> 4, cg = tid & 15;
  float mv0 = mred[0][row], mv1 = mred[1][row], mv2 = mred[2][row], mv3 = mred[3][row];
  float M = fmaxf(fmaxf(mv0, mv1), fmaxf(mv2, mv3));
  const float w0 = __expf(mv0 - M), w1 = __expf(mv1 - M);
  const float w2 = __expf(mv2 - M), w3 = __expf(mv3 - M);
  const float L = lred[0][row] * w0 + lred[1][row] * w1 +
                  lred[2][row] * w2 + lred[3][row] * w3;
  f32x4 acc = ored[0][row * 17 + cg] * w0 + ored[1][row * 17 + cg] * w1 +
              ored[2][row * 17 + cg] * w2 + ored[3][row * 17 + cg] * w3;
  acc *= (1.0f / L);
  *(f32x4*)(out + ((size_t)(b * SEQ + q0 + row)) * HSZ + cg * 4) = acc;
}

extern "C" void kernel_launch(void* const* d_in, const int* in_sizes, int n_in,
                              void* d_out, int out_size, void* d_ws, size_t ws_size,
                              hipStream_t stream) {
  const float* query = (const float*)d_in[0];
  const float* key   = (const float*)d_in[1];
  const float* value = (const float*)d_in[2];
  const float* Wq    = (const float*)d_in[3];
  const float* Wk    = (const float*)d_in[4];
  const float* Wv    = (const float*)d_in[5];

  char* ws = (char*)d_ws;
  short* wfrag = (short*)ws;                                  // 384 KiB
  short* qb    = (short*)(ws + (3 << 17));                    // 2 MiB
  short* kb    = (short*)(ws + (3 << 17) + (1 << 21));        // 2 MiB
  short* vT    = (short*)(ws + (3 << 17) + (2 << 21));        // 2 MiB
  float* outp  = (float*)d_out;

  hipLaunchKernelGGL(w_prep, dim3(64), dim3(256), 0, stream, Wq, Wk, Wv, wfrag);
  hipLaunchKernelGGL(proj, dim3(256, 3), dim3(256), 0, stream,
                     query, key, value, wfrag, qb, kb, vT);
  hipLaunchKernelGGL(attn, dim3(1024), dim3(256), 0, stream, qb, kb, vT, outp);
}